// Round 11
// baseline (169.381 us; speedup 1.0000x reference)
//
#include <hip/hip_runtime.h>

#define T_DIM 20
#define K_DIM 50
#define V_DIM 50000
#define D_DIM 200
#define NEG_TOPK 20
#define M_DIM (K_DIM * NEG_TOPK)   // 1000 candidates per time slice
#define TEMP_INV (1.0f / 0.07f)
#define POOL_CAP 512
#define STATIC_THR 3.0f            // pool keeps all elements >= 3.0
#define NV4 (V_DIM / 4)            // 12500

// monotone key: order(key) == (value desc, index asc) matches jax.lax.top_k
__device__ __forceinline__ unsigned long long make_key(float f, int idx) {
  unsigned u  = __float_as_uint(f);
  unsigned mv = ((int)u < 0) ? ~u : (u | 0x80000000u);
  return ((unsigned long long)mv << 32) |
         (unsigned long long)(0xFFFFFFFFu - (unsigned)idx);
}

__device__ __forceinline__ unsigned long long wave_max_u64(unsigned long long k) {
#pragma unroll
  for (int off = 32; off; off >>= 1) {
    unsigned long long o = __shfl_xor(k, off, 64);
    if (o > k) k = o;
  }
  return k;
}

// ---------------------------------------------------------------------------
// Kernel 1: PURE streaming filter (codegen-isolated; R6/R7/R10 showed tail
// code in the scan kernel perturbs the emitted load schedule). Per row:
// R3's exact scan loop -> LDS pool of elements >= 3.0 (E~67, Poisson), then
// a coalesced 4KB write-out of the pool + count. Nothing else.
// ---------------------------------------------------------------------------
__global__ __launch_bounds__(512) void scan_kernel(const float* __restrict__ beta,
                                                   unsigned long long* __restrict__ gpool,
                                                   int* __restrict__ gcnt) {
  const int row = blockIdx.x;           // 0..999
  const int tid = threadIdx.x;
  const float4* __restrict__ b4 = (const float4*)(beta + (size_t)row * V_DIM);

  __shared__ unsigned long long pool[POOL_CAP];
  __shared__ int cnt;
  if (tid == 0) cnt = 0;
  __syncthreads();

  for (int i = tid; i < NV4; i += 512) {
    float4 v = b4[i];
    const int base = i * 4;
#pragma unroll
    for (int e = 0; e < 4; ++e) {
      float f = (e == 0) ? v.x : (e == 1) ? v.y : (e == 2) ? v.z : v.w;
      if (f >= STATIC_THR) {
        int p = atomicAdd(&cnt, 1);
        if (p < POOL_CAP) pool[p] = make_key(f, base + e);
      }
    }
  }
  __syncthreads();

  const int cw = cnt < POOL_CAP ? cnt : POOL_CAP;
  for (int i = tid; i < cw; i += 512)
    gpool[(size_t)row * POOL_CAP + i] = pool[i];
  if (tid == 0) gcnt[row] = cnt;
}

// ---------------------------------------------------------------------------
// Kernel 2: per time slice t (20 blocks x 256 = 4 waves):
//  (a) each wave selects the exact top-20 for rows rl = wid, wid+4, ... of
//      this t from the pooled keys (<=8 keys/lane, 20 barrier-free rounds of
//      wave-max with strict-key exclusion; exact jax tie order). Fallback
//      (cnt<20 or >POOL_CAP, p~1e-12): exact per-wave 20-round rescan of the
//      beta row (L2/L3-hot). Results to LDS sel[1000].
//  (b) dedup + wc==0 filter (set semantics) -> vlist/vcnt. No global topk.
// ---------------------------------------------------------------------------
#define BM_WORDS ((V_DIM + 31) / 32)    // 1563
__global__ __launch_bounds__(256) void select_bv_kernel(const float* __restrict__ beta,
                                                        const unsigned long long* __restrict__ gpool,
                                                        const int* __restrict__ gcnt,
                                                        const int* __restrict__ wc,
                                                        int* __restrict__ vlist,
                                                        int* __restrict__ vcnt) {
  const int t    = blockIdx.x;
  const int tid  = threadIdx.x;
  const int lane = tid & 63;
  const int wid  = tid >> 6;

  __shared__ int      sel[M_DIM];       // top-20 word ids for the 50 rows
  __shared__ unsigned bm[BM_WORDS];
  __shared__ int      cnt;

  for (int i = tid; i < BM_WORDS; i += 256) bm[i] = 0u;
  if (tid == 0) cnt = 0;

  // (a) selection: wave wid handles rows rl = wid, wid+4, ...
  for (int rl = wid; rl < K_DIM; rl += 4) {
    const int row = t * K_DIM + rl;
    const int c   = gcnt[row];
    if (c >= NEG_TOPK && c <= POOL_CAP) {
      const unsigned long long* __restrict__ pp = gpool + (size_t)row * POOL_CAP;
      unsigned long long kk[8];
#pragma unroll
      for (int j = 0; j < 8; ++j) {
        int p = lane + (j << 6);
        kk[j] = (p < c) ? pp[p] : 0ull;
      }
      unsigned long long kprev = ~0ull;
      for (int r = 0; r < NEG_TOPK; ++r) {
        unsigned long long b = 0ull;
#pragma unroll
        for (int j = 0; j < 8; ++j)
          if (kk[j] < kprev && kk[j] > b) b = kk[j];
        b = wave_max_u64(b);
        if (lane == 0)
          sel[rl * NEG_TOPK + r] =
              (int)(0xFFFFFFFFu - (unsigned)(b & 0xFFFFFFFFull));
        kprev = b;
      }
    } else {
      // exact per-wave fallback: 20 rounds over the full row (cached)
      const float4* __restrict__ b4 = (const float4*)(beta + (size_t)row * V_DIM);
      unsigned long long kprev = ~0ull;
      for (int r = 0; r < NEG_TOPK; ++r) {
        unsigned long long b = 0ull;
        for (int i = lane; i < NV4; i += 64) {
          float4 v = b4[i];
          const int base = i * 4;
#pragma unroll
          for (int e = 0; e < 4; ++e) {
            float f = (e == 0) ? v.x : (e == 1) ? v.y : (e == 2) ? v.z : v.w;
            unsigned long long k = make_key(f, base + e);
            if (k < kprev && k > b) b = k;
          }
        }
        b = wave_max_u64(b);
        if (lane == 0)
          sel[rl * NEG_TOPK + r] =
              (int)(0xFFFFFFFFu - (unsigned)(b & 0xFFFFFFFFull));
        kprev = b;
      }
    }
  }
  __syncthreads();

  // (b) dedup + zero-count filter (set semantics; which dup survives is
  // irrelevant — identical sim rows)
  for (int c = tid; c < M_DIM; c += 256) {
    int w = sel[c];
    if (wc[t * V_DIM + w] == 0) {
      unsigned bit = 1u << (w & 31);
      unsigned old = atomicOr(&bm[w >> 5], bit);
      if (!(old & bit)) {
        int p = atomicAdd(&cnt, 1);
        vlist[t * M_DIM + p] = w;
      }
    }
  }
  __syncthreads();
  if (tid == 0) vcnt[t] = cnt;
}

// ---------------------------------------------------------------------------
// Kernel 3: lse per row, XCD-pinned grid (R9). Grid = 1200: xcd=bid&7,
// slot=bid>>3; t = xcd + 8*(slot/50), k = slot%50; t>=20 dummies exit.
// No fences/tickets (R4/R8: device-scope fences cost 12-18 µs).
// ---------------------------------------------------------------------------
__global__ __launch_bounds__(256) void lse_kernel(const float* __restrict__ temb,
                                                  const float* __restrict__ wemb,
                                                  const int* __restrict__ vlist,
                                                  const int* __restrict__ vcnt,
                                                  float* __restrict__ lse_out) {
  const int xcd  = blockIdx.x & 7;
  const int slot = blockIdx.x >> 3;
  const int t    = xcd + ((slot / K_DIM) << 3);
  if (t >= T_DIM) return;               // dummy block
  const int k    = slot % K_DIM;
  const int row  = t * K_DIM + k;
  const int tid  = threadIdx.x;
  const int lane = tid & 63;
  const int wid  = tid >> 6;
  const int cnt  = vcnt[t];

  __shared__ float4 tvs[D_DIM / 4];  // 50 float4: topic embedding row
  __shared__ float  sim[M_DIM];
  __shared__ float  rbuf[8];

  if (cnt == 0) {
    if (tid == 0) lse_out[row] = 0.0f;
    return;
  }

  if (tid < D_DIM / 4)
    tvs[tid] = ((const float4*)(temb + (size_t)row * D_DIM))[tid];
  __syncthreads();

  const int l7 = lane & 7;
  const int g  = lane >> 3;          // candidate sub-slot 0..7 within wave
  for (int c0 = wid * 8; c0 < cnt; c0 += 32) {
    const int c = c0 + g;
    float acc = 0.f;
    if (c < cnt) {
      const int w = vlist[t * M_DIM + c];
      const float4* __restrict__ wr = (const float4*)(wemb + (size_t)w * D_DIM);
#pragma unroll
      for (int m = 0; m < 6; ++m) {        // d = l7 + 8m, < 50 for m<6
        const int d = l7 + (m << 3);
        float4 a = tvs[d];
        float4 b = wr[d];
        acc = fmaf(a.x, b.x, acc);
        acc = fmaf(a.y, b.y, acc);
        acc = fmaf(a.z, b.z, acc);
        acc = fmaf(a.w, b.w, acc);
      }
      if (l7 < 2) {                        // d in {48,49}
        const int d = l7 + 48;
        float4 a = tvs[d];
        float4 b = wr[d];
        acc = fmaf(a.x, b.x, acc);
        acc = fmaf(a.y, b.y, acc);
        acc = fmaf(a.z, b.z, acc);
        acc = fmaf(a.w, b.w, acc);
      }
    }
    acc += __shfl_xor(acc, 1, 64);
    acc += __shfl_xor(acc, 2, 64);
    acc += __shfl_xor(acc, 4, 64);
    if (l7 == 0 && c < cnt) sim[c] = acc * TEMP_INV;
  }
  __syncthreads();

  float m = -3.0e38f;
  for (int c = tid; c < cnt; c += 256) m = fmaxf(m, sim[c]);
#pragma unroll
  for (int off = 32; off; off >>= 1) m = fmaxf(m, __shfl_xor(m, off, 64));
  if (lane == 0) rbuf[wid] = m;
  __syncthreads();
  m = fmaxf(fmaxf(rbuf[0], rbuf[1]), fmaxf(rbuf[2], rbuf[3]));

  float s = 0.f;
  for (int c = tid; c < cnt; c += 256) s += expf(sim[c] - m);
#pragma unroll
  for (int off = 32; off; off >>= 1) s += __shfl_xor(s, off, 64);
  if (lane == 0) rbuf[4 + wid] = s;
  __syncthreads();
  if (tid == 0) {
    float tot = rbuf[4] + rbuf[5] + rbuf[6] + rbuf[7];
    lse_out[row] = m + logf(tot);
  }
}

// ---------------------------------------------------------------------------
// Kernel 4: final scalar. loss = sum_t(mean_k lse) / count(t with any valid).
// ---------------------------------------------------------------------------
__global__ void final_kernel(const float* __restrict__ lse,
                             const int* __restrict__ vcnt,
                             float* __restrict__ out) {
  const int t = threadIdx.x;           // 64 threads, t < 20 active
  float loss = 0.f, flag = 0.f;
  if (t < T_DIM && vcnt[t] > 0) {
    float s = 0.f;
    for (int k = 0; k < K_DIM; ++k) s += lse[t * K_DIM + k];
    loss = s * (1.0f / K_DIM);
    flag = 1.f;
  }
#pragma unroll
  for (int off = 32; off; off >>= 1) {
    loss += __shfl_down(loss, off, 64);
    flag += __shfl_down(flag, off, 64);
  }
  if (t == 0)
    out[0] = (flag > 0.f) ? loss * (1.0f / fmaxf(flag, 1.f)) : 0.f;  // WEIGHT_UWE=1
}

// ---------------------------------------------------------------------------
extern "C" void kernel_launch(void* const* d_in, const int* in_sizes, int n_in,
                              void* d_out, int out_size, void* d_ws, size_t ws_size,
                              hipStream_t stream) {
  const int*   wc   = (const int*)d_in[0];    // time_wordcount [T,V] int32
  const float* beta = (const float*)d_in[1];  // beta [T,K,V] f32
  const float* temb = (const float*)d_in[2];  // topic_embeddings [T,K,D] f32
  const float* wemb = (const float*)d_in[3];  // word_embeddings [V,D] f32

  // ws layout: gpool 4096000 | gcnt 4000 | vlist 80000 | vcnt 128 | lse 4000
  char* ws = (char*)d_ws;
  unsigned long long* gpool = (unsigned long long*)(ws + 0);
  int*   gcnt  = (int*)(ws + 4096000);
  int*   vlist = (int*)(ws + 4100096);
  int*   vcnt  = (int*)(ws + 4180096);
  float* lse   = (float*)(ws + 4180224);
  float* out   = (float*)d_out;

  scan_kernel<<<T_DIM * K_DIM, 512, 0, stream>>>(beta, gpool, gcnt);
  select_bv_kernel<<<T_DIM, 256, 0, stream>>>(beta, gpool, gcnt, wc, vlist, vcnt);
  lse_kernel<<<1200, 256, 0, stream>>>(temb, wemb, vlist, vcnt, lse);
  final_kernel<<<1, 64, 0, stream>>>(lse, vcnt, out);
}

// Round 12
// 67.486 us; speedup vs baseline: 2.5099x; 2.5099x over previous
//
#include <hip/hip_runtime.h>

#define T_DIM 20
#define K_DIM 50
#define V_DIM 50000
#define D_DIM 200
#define NEG_TOPK 20
#define M_DIM (K_DIM * NEG_TOPK)   // 1000 candidates per time slice
#define TEMP_INV (1.0f / 0.07f)
#define POOL_CAP 512
#define STATIC_THR 3.0f            // pool keeps all elements >= 3.0

// monotone key: order(key) == (value desc, index asc) matches jax.lax.top_k
__device__ __forceinline__ unsigned long long make_key(float f, int idx) {
  unsigned u  = __float_as_uint(f);
  unsigned mv = ((int)u < 0) ? ~u : (u | 0x80000000u);
  return ((unsigned long long)mv << 32) |
         (unsigned long long)(0xFFFFFFFFu - (unsigned)idx);
}

__device__ __forceinline__ unsigned long long wave_max_u64(unsigned long long k) {
#pragma unroll
  for (int off = 32; off; off >>= 1) {
    unsigned long long o = __shfl_xor(k, off, 64);
    if (o > k) k = o;
  }
  return k;
}

// ---------------------------------------------------------------------------
// Kernel 1: exact top-20 per row = t*K+k. BYTE-IDENTICAL to the R3 version
// (68.8 µs total; compiler emits a deep-batched load stream here). R6/R7
// proved appending tail code tanks the register allocator (48->24 VGPR) and
// serializes the loads; R11 proved concentrating selection into few blocks
// is latency-death (122 µs @ 1.4% VALUBusy). DO NOT modify this kernel.
// ---------------------------------------------------------------------------
__global__ __launch_bounds__(512) void topk_kernel(const float* __restrict__ beta,
                                                   int* __restrict__ topk_idx) {
  const int row  = blockIdx.x;          // 0..999
  const int tid  = threadIdx.x;
  const int lane = tid & 63;
  const int wid  = tid >> 6;
  const float4* __restrict__ b4 = (const float4*)(beta + (size_t)row * V_DIM);

  __shared__ unsigned long long pool[POOL_CAP];
  __shared__ int cnt;
  __shared__ unsigned long long wmax[8];
  if (tid == 0) cnt = 0;
  __syncthreads();

  // ---- scan: 1 compare per element, rare append ----
  for (int i = tid; i < V_DIM / 4; i += 512) {
    float4 v = b4[i];
    const int base = i * 4;
#pragma unroll
    for (int e = 0; e < 4; ++e) {
      float f = (e == 0) ? v.x : (e == 1) ? v.y : (e == 2) ? v.z : v.w;
      if (f >= STATIC_THR) {
        int p = atomicAdd(&cnt, 1);
        if (p < POOL_CAP) pool[p] = make_key(f, base + e);
      }
    }
  }
  __syncthreads();
  const int count = cnt;

  if (count >= NEG_TOPK && count <= POOL_CAP) {
    if (wid != 0) return;              // selection is wave-0-only, no barriers
    unsigned long long kk[8];
#pragma unroll
    for (int j = 0; j < 8; ++j) {
      int p = lane + (j << 6);
      kk[j] = (p < count) ? pool[p] : 0ull;
    }
    unsigned long long kprev = ~0ull;
    for (int r = 0; r < NEG_TOPK; ++r) {
      unsigned long long b = 0ull;
#pragma unroll
      for (int j = 0; j < 8; ++j)
        if (kk[j] < kprev && kk[j] > b) b = kk[j];
      b = wave_max_u64(b);
      if (lane == 0)
        topk_idx[row * NEG_TOPK + r] =
            (int)(0xFFFFFFFFu - (unsigned)(b & 0xFFFFFFFFull));
      kprev = b;
    }
  } else {
    // ---- fallback: 20 rounds of block argmax over the row (L2-hot) ----
    unsigned long long kprev = ~0ull;
    for (int r = 0; r < NEG_TOPK; ++r) {
      unsigned long long b = 0ull;
      for (int i = tid; i < V_DIM / 4; i += 512) {
        float4 v = b4[i];
        const int base = i * 4;
#pragma unroll
        for (int e = 0; e < 4; ++e) {
          float f = (e == 0) ? v.x : (e == 1) ? v.y : (e == 2) ? v.z : v.w;
          unsigned long long k = make_key(f, base + e);
          if (k < kprev && k > b) b = k;
        }
      }
      b = wave_max_u64(b);
      if (lane == 0) wmax[wid] = b;
      __syncthreads();
      unsigned long long bmax = wmax[0];
#pragma unroll
      for (int w = 1; w < 8; ++w) bmax = wmax[w] > bmax ? wmax[w] : bmax;
      if (tid == 0)
        topk_idx[row * NEG_TOPK + r] =
            (int)(0xFFFFFFFFu - (unsigned)(bmax & 0xFFFFFFFFull));
      kprev = bmax;
      __syncthreads();
    }
  }
}

// ---------------------------------------------------------------------------
// Kernel 2: per time slice t, unique valid candidates (wc==0, set semantics;
// which duplicate survives is irrelevant — identical sim rows). R3-verbatim.
// ---------------------------------------------------------------------------
#define BM_WORDS ((V_DIM + 31) / 32)    // 1563
__global__ __launch_bounds__(256) void build_valid_kernel(const int* __restrict__ wc,
                                                          const int* __restrict__ topk,
                                                          int* __restrict__ vlist,
                                                          int* __restrict__ vcnt) {
  const int t = blockIdx.x;
  __shared__ unsigned bm[BM_WORDS];
  __shared__ int cnt;
  for (int i = threadIdx.x; i < BM_WORDS; i += 256) bm[i] = 0u;
  if (threadIdx.x == 0) cnt = 0;
  __syncthreads();
  for (int c = threadIdx.x; c < M_DIM; c += 256) {
    int w = topk[t * M_DIM + c];
    if (wc[t * V_DIM + w] == 0) {
      unsigned bit = 1u << (w & 31);
      unsigned old = atomicOr(&bm[w >> 5], bit);
      if (!(old & bit)) {
        int p = atomicAdd(&cnt, 1);
        vlist[t * M_DIM + p] = w;
      }
    }
  }
  __syncthreads();
  if (threadIdx.x == 0) vcnt[t] = cnt;
}

// ---------------------------------------------------------------------------
// Kernel 3: lse per row, XCD-pinned grid (R9, −1µs). Grid = 1200: xcd=bid&7,
// slot=bid>>3; t = xcd + 8*(slot/50), k = slot%50; t>=20 dummies exit.
// No fences/tickets (R4/R8: device-scope fences cost 12-18 µs).
// ---------------------------------------------------------------------------
__global__ __launch_bounds__(256) void lse_kernel(const float* __restrict__ temb,
                                                  const float* __restrict__ wemb,
                                                  const int* __restrict__ vlist,
                                                  const int* __restrict__ vcnt,
                                                  float* __restrict__ lse_out) {
  const int xcd  = blockIdx.x & 7;
  const int slot = blockIdx.x >> 3;
  const int t    = xcd + ((slot / K_DIM) << 3);
  if (t >= T_DIM) return;               // dummy block
  const int k    = slot % K_DIM;
  const int row  = t * K_DIM + k;
  const int tid  = threadIdx.x;
  const int lane = tid & 63;
  const int wid  = tid >> 6;
  const int cnt  = vcnt[t];

  __shared__ float4 tvs[D_DIM / 4];  // 50 float4: topic embedding row
  __shared__ float  sim[M_DIM];
  __shared__ float  rbuf[8];

  if (cnt == 0) {
    if (tid == 0) lse_out[row] = 0.0f;
    return;
  }

  if (tid < D_DIM / 4)
    tvs[tid] = ((const float4*)(temb + (size_t)row * D_DIM))[tid];
  __syncthreads();

  const int l7 = lane & 7;
  const int g  = lane >> 3;          // candidate sub-slot 0..7 within wave
  for (int c0 = wid * 8; c0 < cnt; c0 += 32) {
    const int c = c0 + g;
    float acc = 0.f;
    if (c < cnt) {
      const int w = vlist[t * M_DIM + c];
      const float4* __restrict__ wr = (const float4*)(wemb + (size_t)w * D_DIM);
#pragma unroll
      for (int m = 0; m < 6; ++m) {        // d = l7 + 8m, < 50 for m<6
        const int d = l7 + (m << 3);
        float4 a = tvs[d];
        float4 b = wr[d];
        acc = fmaf(a.x, b.x, acc);
        acc = fmaf(a.y, b.y, acc);
        acc = fmaf(a.z, b.z, acc);
        acc = fmaf(a.w, b.w, acc);
      }
      if (l7 < 2) {                        // d in {48,49}
        const int d = l7 + 48;
        float4 a = tvs[d];
        float4 b = wr[d];
        acc = fmaf(a.x, b.x, acc);
        acc = fmaf(a.y, b.y, acc);
        acc = fmaf(a.z, b.z, acc);
        acc = fmaf(a.w, b.w, acc);
      }
    }
    acc += __shfl_xor(acc, 1, 64);
    acc += __shfl_xor(acc, 2, 64);
    acc += __shfl_xor(acc, 4, 64);
    if (l7 == 0 && c < cnt) sim[c] = acc * TEMP_INV;
  }
  __syncthreads();

  float m = -3.0e38f;
  for (int c = tid; c < cnt; c += 256) m = fmaxf(m, sim[c]);
#pragma unroll
  for (int off = 32; off; off >>= 1) m = fmaxf(m, __shfl_xor(m, off, 64));
  if (lane == 0) rbuf[wid] = m;
  __syncthreads();
  m = fmaxf(fmaxf(rbuf[0], rbuf[1]), fmaxf(rbuf[2], rbuf[3]));

  float s = 0.f;
  for (int c = tid; c < cnt; c += 256) s += expf(sim[c] - m);
#pragma unroll
  for (int off = 32; off; off >>= 1) s += __shfl_xor(s, off, 64);
  if (lane == 0) rbuf[4 + wid] = s;
  __syncthreads();
  if (tid == 0) {
    float tot = rbuf[4] + rbuf[5] + rbuf[6] + rbuf[7];
    lse_out[row] = m + logf(tot);
  }
}

// ---------------------------------------------------------------------------
// Kernel 4: final scalar. loss = sum_t(mean_k lse) / count(t with any valid).
// ---------------------------------------------------------------------------
__global__ void final_kernel(const float* __restrict__ lse,
                             const int* __restrict__ vcnt,
                             float* __restrict__ out) {
  const int t = threadIdx.x;           // 64 threads, t < 20 active
  float loss = 0.f, flag = 0.f;
  if (t < T_DIM && vcnt[t] > 0) {
    float s = 0.f;
    for (int k = 0; k < K_DIM; ++k) s += lse[t * K_DIM + k];
    loss = s * (1.0f / K_DIM);
    flag = 1.f;
  }
#pragma unroll
  for (int off = 32; off; off >>= 1) {
    loss += __shfl_down(loss, off, 64);
    flag += __shfl_down(flag, off, 64);
  }
  if (t == 0)
    out[0] = (flag > 0.f) ? loss * (1.0f / fmaxf(flag, 1.f)) : 0.f;  // WEIGHT_UWE=1
}

// ---------------------------------------------------------------------------
extern "C" void kernel_launch(void* const* d_in, const int* in_sizes, int n_in,
                              void* d_out, int out_size, void* d_ws, size_t ws_size,
                              hipStream_t stream) {
  const int*   wc   = (const int*)d_in[0];    // time_wordcount [T,V] int32
  const float* beta = (const float*)d_in[1];  // beta [T,K,V] f32
  const float* temb = (const float*)d_in[2];  // topic_embeddings [T,K,D] f32
  const float* wemb = (const float*)d_in[3];  // word_embeddings [V,D] f32

  // ws layout: topk 80000B | vlist 80000B | vcnt 128B | lse 4000B
  char* ws = (char*)d_ws;
  int*   topk_idx = (int*)(ws + 0);
  int*   vlist    = (int*)(ws + 80000);
  int*   vcnt     = (int*)(ws + 160000);
  float* lse      = (float*)(ws + 160128);
  float* out      = (float*)d_out;

  topk_kernel<<<T_DIM * K_DIM, 512, 0, stream>>>(beta, topk_idx);
  build_valid_kernel<<<T_DIM, 256, 0, stream>>>(wc, topk_idx, vlist, vcnt);
  lse_kernel<<<1200, 256, 0, stream>>>(temb, wemb, vlist, vcnt, lse);
  final_kernel<<<1, 64, 0, stream>>>(lse, vcnt, out);
}